// Round 3
// baseline (3876.747 us; speedup 1.0000x reference)
//
#include <hip/hip_runtime.h>
#include <hip/hip_bf16.h>

typedef unsigned short u16;
typedef __attribute__((ext_vector_type(8))) __bf16 bf16x8;
typedef __attribute__((ext_vector_type(8))) unsigned short us8;
typedef __attribute__((ext_vector_type(4))) float f32x4;

#define BB 2
#define LL 1024
#define DD 768
#define HH 12

// round-to-nearest-even f32 -> bf16
__device__ __forceinline__ u16 f2b(float v) {
  unsigned u = __builtin_bit_cast(unsigned, v);
  return (u16)((u + 0x7fffu + ((u >> 16) & 1u)) >> 16);
}
__device__ __forceinline__ float b2f(u16 b) {
  return __builtin_bit_cast(float, (unsigned)b << 16);
}

__global__ void k_cast(const float* __restrict__ in, u16* __restrict__ out, int n) {
  int i = blockIdx.x * blockDim.x + threadIdx.x;
  if (i < n) out[i] = f2b(in[i]);
}

// ---------------------------------------------------------------------------
// C[m,n] = sum_k A[m,k] * Bt[n,k]  (both bf16, fp32 accum). 64x64 tile, BK=32.
// ---------------------------------------------------------------------------
__global__ __launch_bounds__(256) void k_gemm_nt(
    const u16* __restrict__ A, int lda, long long sAb, long long sAh,
    const u16* __restrict__ Bt, int ldb, long long sBb, long long sBh,
    float* __restrict__ Cf, u16* __restrict__ Cb, int ldc, long long sCb, long long sCh,
    const float* __restrict__ bias, int M, int N, int K, int nInner)
{
  __shared__ __align__(16) u16 As[64][40];
  __shared__ __align__(16) u16 Bs[64][40];
  int z = blockIdx.z, zb = z / nInner, zh = z - zb * nInner;
  A  += zb * sAb + zh * sAh;
  Bt += zb * sBb + zh * sBh;
  long long coff = zb * sCb + zh * sCh;
  int m0 = blockIdx.y * 64, n0 = blockIdx.x * 64;
  int tid = threadIdx.x, lane = tid & 63, w = tid >> 6;
  int wm = (w >> 1) * 32, wn = (w & 1) * 32;
  int arow = tid >> 2, acol = (tid & 3) * 8;
  int frow = lane & 15, kf = (lane >> 4) * 8;
  f32x4 acc[2][2] = {};
  for (int k0 = 0; k0 < K; k0 += 32) {
    *(uint4*)&As[arow][acol] = *(const uint4*)&A[(size_t)(m0 + arow) * lda + k0 + acol];
    *(uint4*)&Bs[arow][acol] = *(const uint4*)&Bt[(size_t)(n0 + arow) * ldb + k0 + acol];
    __syncthreads();
    bf16x8 af0 = *(const bf16x8*)&As[wm + frow][kf];
    bf16x8 af1 = *(const bf16x8*)&As[wm + 16 + frow][kf];
    bf16x8 bg0 = *(const bf16x8*)&Bs[wn + frow][kf];
    bf16x8 bg1 = *(const bf16x8*)&Bs[wn + 16 + frow][kf];
    acc[0][0] = __builtin_amdgcn_mfma_f32_16x16x32_bf16(af0, bg0, acc[0][0], 0, 0, 0);
    acc[0][1] = __builtin_amdgcn_mfma_f32_16x16x32_bf16(af0, bg1, acc[0][1], 0, 0, 0);
    acc[1][0] = __builtin_amdgcn_mfma_f32_16x16x32_bf16(af1, bg0, acc[1][0], 0, 0, 0);
    acc[1][1] = __builtin_amdgcn_mfma_f32_16x16x32_bf16(af1, bg1, acc[1][1], 0, 0, 0);
    __syncthreads();
  }
  int cr = (lane >> 4) * 4, cc = lane & 15;
  for (int mi = 0; mi < 2; mi++)
    for (int ni = 0; ni < 2; ni++) {
      int col = n0 + wn + ni * 16 + cc;
      float bval = bias ? bias[col] : 0.f;
      #pragma unroll
      for (int j = 0; j < 4; j++) {
        int row = m0 + wm + mi * 16 + cr + j;
        float v = acc[mi][ni][j] + bval;
        size_t idx = (size_t)coff + (size_t)row * ldc + col;
        if (Cf) Cf[idx] = v;
        if (Cb) Cb[idx] = f2b(v);
      }
    }
}

// ---------------------------------------------------------------------------
// C[m,n] = sum_k A[m,k] * B[k,n]  (row-major B). Same tiling; B staged transposed.
// ---------------------------------------------------------------------------
__global__ __launch_bounds__(256) void k_gemm_nn(
    const u16* __restrict__ A, int lda, long long sAb, long long sAh,
    const u16* __restrict__ Bm, int ldb, long long sBb, long long sBh,
    float* __restrict__ Cf, u16* __restrict__ Cb, int ldc, long long sCb, long long sCh,
    const float* __restrict__ bias, int M, int N, int K, int nInner)
{
  __shared__ __align__(16) u16 As[64][40];
  __shared__ __align__(16) u16 Bs[64][40];
  int z = blockIdx.z, zb = z / nInner, zh = z - zb * nInner;
  A  += zb * sAb + zh * sAh;
  Bm += zb * sBb + zh * sBh;
  long long coff = zb * sCb + zh * sCh;
  int m0 = blockIdx.y * 64, n0 = blockIdx.x * 64;
  int tid = threadIdx.x, lane = tid & 63, w = tid >> 6;
  int wm = (w >> 1) * 32, wn = (w & 1) * 32;
  int arow = tid >> 2, acol = (tid & 3) * 8;
  int brow = tid >> 3, bcol = (tid & 7) * 8;
  int frow = lane & 15, kf = (lane >> 4) * 8;
  f32x4 acc[2][2] = {};
  for (int k0 = 0; k0 < K; k0 += 32) {
    *(uint4*)&As[arow][acol] = *(const uint4*)&A[(size_t)(m0 + arow) * lda + k0 + acol];
    union { uint4 v; u16 s[8]; } t4;
    t4.v = *(const uint4*)&Bm[(size_t)(k0 + brow) * ldb + n0 + bcol];
    #pragma unroll
    for (int j = 0; j < 8; j++) Bs[bcol + j][brow] = t4.s[j];
    __syncthreads();
    bf16x8 af0 = *(const bf16x8*)&As[wm + frow][kf];
    bf16x8 af1 = *(const bf16x8*)&As[wm + 16 + frow][kf];
    bf16x8 bg0 = *(const bf16x8*)&Bs[wn + frow][kf];
    bf16x8 bg1 = *(const bf16x8*)&Bs[wn + 16 + frow][kf];
    acc[0][0] = __builtin_amdgcn_mfma_f32_16x16x32_bf16(af0, bg0, acc[0][0], 0, 0, 0);
    acc[0][1] = __builtin_amdgcn_mfma_f32_16x16x32_bf16(af0, bg1, acc[0][1], 0, 0, 0);
    acc[1][0] = __builtin_amdgcn_mfma_f32_16x16x32_bf16(af1, bg0, acc[1][0], 0, 0, 0);
    acc[1][1] = __builtin_amdgcn_mfma_f32_16x16x32_bf16(af1, bg1, acc[1][1], 0, 0, 0);
    __syncthreads();
  }
  int cr = (lane >> 4) * 4, cc = lane & 15;
  for (int mi = 0; mi < 2; mi++)
    for (int ni = 0; ni < 2; ni++) {
      int col = n0 + wn + ni * 16 + cc;
      float bval = bias ? bias[col] : 0.f;
      #pragma unroll
      for (int j = 0; j < 4; j++) {
        int row = m0 + wm + mi * 16 + cr + j;
        float v = acc[mi][ni][j] + bval;
        size_t idx = (size_t)coff + (size_t)row * ldc + col;
        if (Cf) Cf[idx] = v;
        if (Cb) Cb[idx] = f2b(v);
      }
    }
}

// ---------------------------------------------------------------------------
// scores[b,h,l,r] += rel[b,l,r,:] . (rq[b,l,h*64+:] + rk[b,r,h*64+:])
// Grid: blk = ((b*256 + ltile4)*8 + rchunk128). Block 256 thr = 4 waves.
// Wave = one l. Lane: r = (tid>>1)&31, p = tid&1 (d-half). 12 h accums/thread.
// rel staged via regs -> bf16 LDS per 32-r chunk (coalesced, read-once HBM).
// ---------------------------------------------------------------------------
__global__ __launch_bounds__(256) void k_relterms(
    const float* __restrict__ rel, const float* __restrict__ rqf,
    const float* __restrict__ rkf, float* __restrict__ scores)
{
  __shared__ __align__(16) float rqs[4][776];   // 12.4 KB, row 3104 B
  __shared__ __align__(16) u16 rels[128][72];   // 18.4 KB, row 144 B
  int blk = blockIdx.x;
  int rc = blk & 7;
  int t  = blk >> 3;
  int b  = t >> 8;
  int l0 = (t & 255) << 2;
  int tid = threadIdx.x;
  int ll = tid >> 6;          // wave index == l_local
  int u  = tid & 63;
  int p  = tid & 1;           // d half
  int rl = (tid >> 1) & 31;   // r local within chunk

  // stage rq[4][768] fp32 (768 float4, 3 per thread)
  #pragma unroll
  for (int j = 0; j < 3; j++) {
    int i = j * 256 + tid;
    int rr = i / 192, cc = (i - rr * 192) * 4;
    *(float4*)&rqs[rr][cc] = *(const float4*)&rqf[((size_t)b * LL + l0 + rr) * DD + cc];
  }

  const float4* relbase = (const float4*)(rel + (((size_t)b * LL + l0 + ll) * LL + rc * 128) * 64);
  float4 st[8];
  // prologue: load chunk 0 (each wave its own l row-run; coalesced)
  #pragma unroll
  for (int j = 0; j < 8; j++) st[j] = relbase[u + j * 64];

  const float4* rq4 = (const float4*)&rqs[ll][0];
  float s[12];
  #pragma unroll
  for (int h = 0; h < 12; h++) s[h] = 0.f;

  for (int c = 0; c < 4; c++) {
    __syncthreads();   // previous chunk's compute done before LDS overwrite
    #pragma unroll
    for (int j = 0; j < 8; j++) {
      int f = u + j * 64;
      int r = f >> 4, dg = f & 15;
      ushort4 w4;
      w4.x = f2b(st[j].x); w4.y = f2b(st[j].y); w4.z = f2b(st[j].z); w4.w = f2b(st[j].w);
      *(ushort4*)&rels[ll * 32 + r][dg * 4] = w4;
    }
    __syncthreads();
    if (c < 3) {
      const float4* nxt = relbase + (size_t)(c + 1) * 512;
      #pragma unroll
      for (int j = 0; j < 8; j++) st[j] = nxt[u + j * 64];
    }
    int rg = rc * 128 + c * 32 + rl;
    const float4* rk4 = (const float4*)(rkf + ((size_t)b * LL + rg) * DD);
    const u16* relrow = &rels[ll * 32 + rl][0];
    #pragma unroll
    for (int h = 0; h < 12; h++) s[h] = 0.f;
    #pragma unroll
    for (int dgh = 0; dgh < 4; dgh++) {
      us8 rv = *(const us8*)&relrow[p * 32 + dgh * 8];
      float f0x = b2f(rv[0]), f0y = b2f(rv[1]), f0z = b2f(rv[2]), f0w = b2f(rv[3]);
      float f1x = b2f(rv[4]), f1y = b2f(rv[5]), f1z = b2f(rv[6]), f1w = b2f(rv[7]);
      int fo = p * 8 + dgh * 2;
      #pragma unroll
      for (int h = 0; h < 12; h++) {
        float4 a0 = rq4[h * 16 + fo], a1 = rq4[h * 16 + fo + 1];
        float4 k0 = rk4[h * 16 + fo], k1 = rk4[h * 16 + fo + 1];
        s[h] += f0x * (a0.x + k0.x) + f0y * (a0.y + k0.y)
              + f0z * (a0.z + k0.z) + f0w * (a0.w + k0.w)
              + f1x * (a1.x + k1.x) + f1y * (a1.y + k1.y)
              + f1z * (a1.z + k1.z) + f1w * (a1.w + k1.w);
      }
    }
    int l = l0 + ll;
    #pragma unroll
    for (int h = 0; h < 12; h++) {
      float tot = s[h] + __shfl_xor(s[h], 1);   // combine d-halves
      if (p == 0) {
        size_t idx = ((size_t)(b * HH + h) * LL + l) * LL + rg;
        scores[idx] += tot;
      }
    }
  }
}

// ---------------------------------------------------------------------------
// Row softmax: x = scores/sqrt(192) + mask[b,r]; probs written bf16 IN-PLACE.
// ---------------------------------------------------------------------------
__global__ __launch_bounds__(256) void k_softmax(float* __restrict__ scores,
                                                 const float* __restrict__ mask)
{
  __shared__ float red[4];
  int z = blockIdx.x;
  int b = z / (HH * LL);
  float* row = scores + (size_t)z * LL;
  int tid = threadIdx.x;
  const float inv = 0.07216878364870322f;  // 1/sqrt(192)
  float4 x = ((const float4*)row)[tid];
  float4 mk = ((const float4*)(mask + (size_t)b * LL))[tid];
  x.x = x.x * inv + mk.x; x.y = x.y * inv + mk.y;
  x.z = x.z * inv + mk.z; x.w = x.w * inv + mk.w;
  float m = fmaxf(fmaxf(x.x, x.y), fmaxf(x.z, x.w));
  for (int i = 1; i < 64; i <<= 1) m = fmaxf(m, __shfl_xor(m, i));
  if ((tid & 63) == 0) red[tid >> 6] = m;
  __syncthreads();
  m = fmaxf(fmaxf(red[0], red[1]), fmaxf(red[2], red[3]));
  float e0 = expf(x.x - m), e1 = expf(x.y - m), e2 = expf(x.z - m), e3 = expf(x.w - m);
  float s = e0 + e1 + e2 + e3;
  for (int i = 1; i < 64; i <<= 1) s += __shfl_xor(s, i);
  __syncthreads();
  if ((tid & 63) == 0) red[tid >> 6] = s;
  __syncthreads();
  float rs = 1.f / (red[0] + red[1] + red[2] + red[3]);
  u16* prow = (u16*)row;
  ushort4 o;
  o.x = f2b(e0 * rs); o.y = f2b(e1 * rs); o.z = f2b(e2 * rs); o.w = f2b(e3 * rs);
  ((ushort4*)prow)[tid] = o;
}

extern "C" void kernel_launch(void* const* d_in, const int* in_sizes, int n_in,
                              void* d_out, int out_size, void* d_ws, size_t ws_size,
                              hipStream_t stream)
{
  const float* hs   = (const float*)d_in[0];
  const float* mask = (const float*)d_in[1];
  const float* rel  = (const float*)d_in[2];
  const float* Wq   = (const float*)d_in[3];
  const float* Wk   = (const float*)d_in[4];
  const float* Wv   = (const float*)d_in[5];
  const float* bv   = (const float*)d_in[6];
  const float* Wo   = (const float*)d_in[7];
  const float* bo   = (const float*)d_in[8];
  float* out = (float*)d_out;

  size_t o = 0;
  char* wsb = (char*)d_ws;
  auto alc = [&](size_t bytes) { void* p = wsb + o; o += (bytes + 255) & ~(size_t)255; return p; };
  u16* hs_bf = (u16*)alc(2048ull * 768 * 2);
  u16* wq_bf = (u16*)alc(768ull * 768 * 2);
  u16* wk_bf = (u16*)alc(768ull * 768 * 2);
  u16* wv_bf = (u16*)alc(768ull * 768 * 2);
  u16* wo_bf = (u16*)alc(768ull * 768 * 2);
  u16* q_bf  = (u16*)alc(2048ull * 768 * 2);
  u16* k_bf  = (u16*)alc(2048ull * 768 * 2);
  u16* v_bf  = (u16*)alc(2048ull * 768 * 2);
  float* rq_f = (float*)alc(2048ull * 768 * 4);
  float* rk_f = (float*)alc(2048ull * 768 * 4);
  u16* att_bf = (u16*)alc(2048ull * 768 * 2);
  float* scores = (float*)alc((size_t)BB * HH * LL * LL * 4);
  (void)ws_size; (void)in_sizes; (void)n_in; (void)out_size;

  k_cast<<<dim3((1572864 + 255) / 256), dim3(256), 0, stream>>>(hs, hs_bf, 1572864);
  k_cast<<<dim3((589824 + 255) / 256), dim3(256), 0, stream>>>(Wq, wq_bf, 589824);
  k_cast<<<dim3((589824 + 255) / 256), dim3(256), 0, stream>>>(Wk, wk_bf, 589824);
  k_cast<<<dim3((589824 + 255) / 256), dim3(256), 0, stream>>>(Wv, wv_bf, 589824);
  k_cast<<<dim3((589824 + 255) / 256), dim3(256), 0, stream>>>(Wo, wo_bf, 589824);

  dim3 gP(768 / 64, 2048 / 64, 1);
  k_gemm_nt<<<gP, 256, 0, stream>>>(hs_bf, 768, 0, 0, wq_bf, 768, 0, 0,
                                    nullptr, q_bf, 768, 0, 0, nullptr, 2048, 768, 768, 1);
  k_gemm_nt<<<gP, 256, 0, stream>>>(hs_bf, 768, 0, 0, wk_bf, 768, 0, 0,
                                    nullptr, k_bf, 768, 0, 0, nullptr, 2048, 768, 768, 1);
  k_gemm_nt<<<gP, 256, 0, stream>>>(hs_bf, 768, 0, 0, wv_bf, 768, 0, 0,
                                    nullptr, v_bf, 768, 0, 0, bv, 2048, 768, 768, 1);
  k_gemm_nn<<<gP, 256, 0, stream>>>(q_bf, 768, 0, 0, wk_bf, 768, 0, 0,
                                    rq_f, nullptr, 768, 0, 0, nullptr, 2048, 768, 768, 1);
  k_gemm_nn<<<gP, 256, 0, stream>>>(k_bf, 768, 0, 0, wq_bf, 768, 0, 0,
                                    rk_f, nullptr, 768, 0, 0, nullptr, 2048, 768, 768, 1);

  dim3 gS(16, 16, 24);
  k_gemm_nt<<<gS, 256, 0, stream>>>(q_bf, 768, 786432LL, 64LL, k_bf, 768, 786432LL, 64LL,
                                    scores, nullptr, 1024, 12582912LL, 1048576LL,
                                    nullptr, 1024, 1024, 64, 12);
  // rel terms: grid = 2 b x 256 l-tiles(4) x 8 r-chunks(128)
  k_relterms<<<dim3(4096), dim3(256), 0, stream>>>(rel, rq_f, rk_f, scores);
  k_softmax<<<dim3(BB * HH * LL), dim3(256), 0, stream>>>(scores, mask);
  dim3 gPV(1, 16, 24);
  k_gemm_nn<<<gPV, 256, 0, stream>>>((u16*)scores, 2048, 25165824LL, 2097152LL,
                                     v_bf, 768, 786432LL, 64LL,
                                     nullptr, att_bf, 768, 786432LL, 64LL,
                                     nullptr, 1024, 64, 1024, 12);
  k_gemm_nt<<<gP, 256, 0, stream>>>(att_bf, 768, 0, 0, wo_bf, 768, 0, 0,
                                    out, nullptr, 768, 0, 0, bo, 2048, 768, 768, 1);
}